// Round 1
// baseline (5955.968 us; speedup 1.0000x reference)
//
#include <hip/hip_runtime.h>

typedef __attribute__((ext_vector_type(8))) short short8;
typedef __attribute__((ext_vector_type(4))) float floatx4;

#define B_   128
#define T_   1024
#define D_   256
#define HS_  512

// workspace layout (bytes)
#define OFF_X   0ull
#define SZ_X    ((size_t)B_*T_*D_*2)            // 64 MiB  x in bf16
#define OFF_W   (OFF_X + SZ_X)
#define SZ_W    ((size_t)16*4*48*64*8*2)        // 3 MiB   weight fragments
#define OFF_H   (OFF_W + SZ_W)
#define SZ_H    ((size_t)2*B_*HS_*2)            // 256 KiB h double buffer (bf16)
#define OFF_C   (OFF_H + SZ_H)                  // 512 u32 flags: 8 groups x 64

__device__ inline unsigned short f2bf(float f){
  union { float f; unsigned u; } v; v.f = f;
  unsigned r = v.u + 0x7FFFu + ((v.u >> 16) & 1u);
  return (unsigned short)(r >> 16);
}

// ---- zero h buffer + flags (ws is poisoned 0xAA every call) ----
__global__ void k_zero(unsigned* __restrict__ hbuf32, unsigned* __restrict__ cnt32){
  int i = blockIdx.x*256 + threadIdx.x;
  if (i < (int)(SZ_H/4)) hbuf32[i] = 0u;
  if (i < 512)           cnt32[i]  = 0u;
}

// ---- convert x fp32 -> bf16 ----
__global__ void k_convx(const float* __restrict__ x, unsigned short* __restrict__ xb){
  size_t i = ((size_t)blockIdx.x*256 + threadIdx.x)*8;
  const float* s = x + i;
  short8 r;
#pragma unroll
  for (int j=0;j<8;j++) r[j] = (short)f2bf(s[j]);
  *(short8*)(void*)(xb + i) = r;
}

// ---- pre-swizzle [W;U] into MFMA B-fragment order, bf16 ----
// flat = (((sub*4 + w)*24 + kt)*2 + nt)*64 + lane, 8 bf16 per flat entry
//   K   = kt*32 + (lane>>4)*8 + j
// GATE-PAIRING column permutation: output col c = lane&15 of acc_nt maps to
//   weight col = gate*HS + sub*32 + w*8 + (lane&7),  gate = nt*2 + ((lane>>3)&1)
// => thread with lane-bit3=0 holds (i,g), bit3=1 holds (f,o) for ONE h-col.
__global__ void k_wfrag(const float* __restrict__ W, const float* __restrict__ U,
                        unsigned short* __restrict__ wf){
  int flat = blockIdx.x*256 + threadIdx.x;       // 0..196607
  int lane = flat & 63;
  int rest = flat >> 6;
  int nt   = rest & 1;
  int kt   = (rest >> 1) % 24;
  int sw   = (rest >> 1) / 24;                   // sub*4 + w
  int w    = sw & 3;
  int sub  = sw >> 2;
  int gate = nt*2 + ((lane >> 3) & 1);
  int colg = gate*HS_ + sub*32 + w*8 + (lane & 7);
  int kbase = kt*32 + (lane >> 4)*8;
  short8 r;
#pragma unroll
  for (int j=0;j<8;j++){
    int k = kbase + j;
    float v = (k < D_) ? W[(size_t)k*2048 + colg] : U[(size_t)(k-D_)*2048 + colg];
    r[j] = (short)f2bf(v);
  }
  *(short8*)(void*)(wf + (size_t)flat*8) = r;
}

// ---- persistent recurrence kernel ----
// grid = 128 WGs x 256 thr. group = wg>>4 owns batch rows [16g,16g+16);
// sub = wg&15 owns h cols [32*sub,32*sub+32); wave w owns h cols w*8..w*8+8
// across all 4 gates. K=768 MFMA 16x16x32 bf16, register-resident B.
//
// Sync protocol (NO __syncthreads in the loop):
//  - per-WAVE flag: after a wave's sc1 h-stores are drained (s_waitcnt
//    vmcnt(0)), lane 0 stores t+1 to flags[sub*4+wave] (relaxed sc1, no RMW).
//  - every wave polls all 64 group flags (lane i loads flags[i], __all).
//    flag>=t+1 also proves that wave finished its A_lds reads for step t,
//    so staging t+1 cannot race a reader of t.
//  - one raw s_barrier after LDS staging orders intra-WG ds_write->ds_read.
// Only sc1 (device-coherent) relaxed atomics -- no __threadfence (R1: full
// L2 wb/inv = 10x slowdown).
__global__ __launch_bounds__(256, 1) void k_lstm(
  const unsigned short* __restrict__ xb,
  const unsigned short* __restrict__ wf,
  const float* __restrict__ bias,
  unsigned short* __restrict__ hbuf,
  unsigned int* __restrict__ flags,
  float* __restrict__ out)
{
  // h fragments only (x lives in registers). Swizzled layout:
  // idx16(kt,q,row) = kt*512 + (q*16 + (row ^ ((q<<1)|(kt&1))))*8  (+half*4)
  // -> staging writes hit all 8 bank-groups per 16-lane phase (was 32-way),
  //    reads stay within one 256B quarter per phase (2-way, free).
  __shared__ unsigned short A_lds[16*512];       // 16 KiB

  const int wg    = blockIdx.x;
  const int group = wg >> 4, sub = wg & 15;
  const int tid   = threadIdx.x;
  const int wave  = tid >> 6, lane = tid & 63;
  const int g16   = group*16;

  // B fragments: 48 x 16B/lane = 192 regs, resident all 1024 steps
  short8 bw[48];
  {
    const unsigned short* wp = wf + (size_t)(sub*4 + wave)*48*512 + (size_t)lane*8;
#pragma unroll
    for (int i=0;i<48;i++) bw[i] = *(const short8*)(const void*)(wp + i*512);
  }

  // elementwise geometry: one h-col per lane, 4 rows
  const int bit3 = (lane >> 3) & 1;
  const int hcol = sub*32 + wave*8 + (lane & 7);
  const int r0   = (lane >> 4) * 4;
  const float b0 = bias[bit3*HS_ + hcol];        // i (bit3=0) or f (bit3=1)
  const float b1 = bias[(2+bit3)*HS_ + hcol];    // g (bit3=0) or o (bit3=1)

  // MFMA A-fragment geometry (per lane)
  const int arow = lane & 15, aq = lane >> 4;
  const unsigned short* xbase = xb + ((size_t)(g16 + arow)*T_)*D_ + aq*8;
  const int se = (aq*16 + (arow ^ (aq<<1)      ))*8;   // even-kt read slot
  const int so = (aq*16 + (arow ^ ((aq<<1)|1)  ))*8;   // odd-kt read slot

  // h staging geometry: thread handles hc = tid&127 (u64 within row), rows
  // 2j + (tid>>7), j=0..7.  Global side: 512B-coalesced per wave.
  const int hc    = tid & 127;
  const int kt_l  = hc >> 3, qs = (hc >> 1) & 3, half = hc & 1;
  const int es    = (qs << 1) | (kt_l & 1);
  const int rbase = tid >> 7;

  unsigned int* myflags = flags + group*64;
  const size_t HSQ = (size_t)B_*T_*HS_;

  float cc[4] = {0.f,0.f,0.f,0.f};               // c-state (valid on bit3=1 lanes)

  short8 xfA[8], xfB[8];
#pragma unroll
  for (int kt=0;kt<8;kt++) xfA[kt] = *(const short8*)(const void*)(xbase + kt*32);

#define LSTM_STEP(TT, XC, XN) {                                                \
  /* 1. wait until h(TT) visible: all 64 wave-flags >= TT */                   \
  if ((TT) > 0){                                                               \
    unsigned fv;                                                               \
    do { fv = __hip_atomic_load(myflags + lane, __ATOMIC_RELAXED,              \
                                __HIP_MEMORY_SCOPE_AGENT);                     \
    } while (!__all((int)(fv >= (unsigned)(TT))));                             \
    __atomic_signal_fence(__ATOMIC_ACQUIRE);                                   \
  }                                                                            \
  /* 2. issue h loads (sc1, coalesced u64) */                                  \
  const unsigned short* hsrc = hbuf + (size_t)((TT)&1)*B_*HS_;                 \
  unsigned long long hv[8];                                                    \
  _Pragma("unroll")                                                            \
  for (int j=0;j<8;j++)                                                        \
    hv[j] = __hip_atomic_load(                                                 \
      (const unsigned long long*)(const void*)(hsrc +                          \
        (size_t)(g16 + 2*j + rbase)*HS_ + hc*4),                               \
      __ATOMIC_RELAXED, __HIP_MEMORY_SCOPE_AGENT);                             \
  /* 3. x prefetch for TT+1 (plain, L1-cached, fragment order) */              \
  { int tn = (TT)+1 < T_ ? (TT)+1 : T_-1;                                      \
    const unsigned short* xp = xbase + (size_t)tn*D_;                          \
    _Pragma("unroll")                                                          \
    for (int kt=0;kt<8;kt++) XN[kt] = *(const short8*)(const void*)(xp+kt*32); \
  }                                                                            \
  /* 4. x-part MFMA from registers -- overlaps h-load latency */               \
  floatx4 acc0 = {0.f,0.f,0.f,0.f}, acc1 = {0.f,0.f,0.f,0.f};                  \
  _Pragma("unroll")                                                            \
  for (int kt=0;kt<8;kt++){                                                    \
    acc0 = __builtin_amdgcn_mfma_f32_16x16x32_bf16(XC[kt], bw[kt*2+0], acc0, 0,0,0); \
    acc1 = __builtin_amdgcn_mfma_f32_16x16x32_bf16(XC[kt], bw[kt*2+1], acc1, 0,0,0); \
  }                                                                            \
  /* 5. stage h into swizzled fragments (conflict-free) */                     \
  _Pragma("unroll")                                                            \
  for (int j=0;j<8;j++){                                                       \
    int row = 2*j + rbase;                                                     \
    *(unsigned long long*)(void*)&A_lds[kt_l*512 + (qs*16 + (row ^ es))*8      \
                                        + half*4] = hv[j];                     \
  }                                                                            \
  asm volatile("s_waitcnt lgkmcnt(0)" ::: "memory");                           \
  __builtin_amdgcn_s_barrier();                                                \
  asm volatile("" ::: "memory");                                               \
  /* 6. h-part MFMA (K=512) */                                                 \
  _Pragma("unroll")                                                            \
  for (int kt=0;kt<16;kt++){                                                   \
    short8 a = *(const short8*)(const void*)&A_lds[kt*512 + ((kt&1) ? so : se)]; \
    acc0 = __builtin_amdgcn_mfma_f32_16x16x32_bf16(a, bw[(8+kt)*2+0], acc0, 0,0,0); \
    acc1 = __builtin_amdgcn_mfma_f32_16x16x32_bf16(a, bw[(8+kt)*2+1], acc1, 0,0,0); \
  }                                                                            \
  /* 7. LSTM cell: (i,g) on bit3=0 lanes, (f,o)+c on bit3=1; one xor-8 shfl */ \
  unsigned short* hdst = hbuf + (size_t)(((TT)+1)&1)*B_*HS_;                   \
  _Pragma("unroll")                                                            \
  for (int r=0;r<4;r++){                                                       \
    float a0 = acc0[r] + b0;                                                   \
    float a1 = acc1[r] + b1;                                                   \
    float s0 = 1.f/(1.f + __expf(-a0));            /* sig(i) | sig(f) */       \
    float e1 = __expf(bit3 ? -a1 : 2.f*a1);                                    \
    float s1 = bit3 ? 1.f/(1.f+e1) : 1.f - 2.f/(e1+1.f); /* sig(o)|tanh(g) */  \
    float p  = s0 * s1;                            /* i*g on bit3=0 */         \
    float pr = __shfl_xor(p, 8, 64);                                           \
    cc[r] = s0*cc[r] + pr;                         /* f*c + i*g  (bit3=1) */   \
    float th = 1.f - 2.f/(__expf(2.f*cc[r])+1.f);                              \
    float hval = s1 * th;                          /* o*tanh(c)  (bit3=1) */   \
    float hprt = __shfl_xor(hval, 1, 64);          /* partner col for pack */  \
    int gr = g16 + r0 + r;                                                     \
    if ((lane & 9) == 8){  /* bit3=1, even h-col: store packed u32 (sc1) */    \
      unsigned pk = (unsigned)f2bf(hval) | ((unsigned)f2bf(hprt) << 16);       \
      __hip_atomic_store((unsigned int*)(void*)(hdst + (size_t)gr*HS_ + hcol), \
                         pk, __ATOMIC_RELAXED, __HIP_MEMORY_SCOPE_AGENT);      \
    }                                                                          \
    if (lane & 8){                                                             \
      out[((size_t)gr*T_ + (TT))*HS_ + hcol] = hval;                           \
      if ((TT) == T_-1){                                                       \
        out[HSQ + (size_t)gr*HS_ + hcol] = hval;                               \
        out[HSQ + (size_t)B_*HS_ + (size_t)gr*HS_ + hcol] = cc[r];             \
      }                                                                        \
    }                                                                          \
  }                                                                            \
  /* 8. per-wave signal: drain own sc1 stores, then flag (no RMW) */           \
  __atomic_signal_fence(__ATOMIC_RELEASE);                                     \
  asm volatile("s_waitcnt vmcnt(0)" ::: "memory");                             \
  if (lane == 0)                                                               \
    __hip_atomic_store(myflags + (sub*4 + wave), (unsigned)((TT)+1),           \
                       __ATOMIC_RELAXED, __HIP_MEMORY_SCOPE_AGENT);            \
}

  for (int t=0; t<T_; t+=2){
    LSTM_STEP(t,   xfA, xfB);
    LSTM_STEP(t+1, xfB, xfA);
  }
#undef LSTM_STEP
}

extern "C" void kernel_launch(void* const* d_in, const int* in_sizes, int n_in,
                              void* d_out, int out_size, void* d_ws, size_t ws_size,
                              hipStream_t stream){
  (void)in_sizes; (void)n_in; (void)out_size; (void)ws_size;
  const float* x    = (const float*)d_in[0];
  const float* W    = (const float*)d_in[1];
  const float* U    = (const float*)d_in[2];
  const float* bias = (const float*)d_in[3];
  char* ws = (char*)d_ws;
  unsigned short* xb = (unsigned short*)(ws + OFF_X);
  unsigned short* wfp= (unsigned short*)(ws + OFF_W);
  unsigned short* hb = (unsigned short*)(ws + OFF_H);
  unsigned int*   fl = (unsigned int*)(ws + OFF_C);
  float* out = (float*)d_out;

  hipLaunchKernelGGL(k_zero,  dim3(256),   dim3(256), 0, stream, (unsigned*)hb, fl);
  hipLaunchKernelGGL(k_convx, dim3((B_*T_*D_/8)/256), dim3(256), 0, stream, x, xb);
  hipLaunchKernelGGL(k_wfrag, dim3(768),   dim3(256), 0, stream, W, U, wfp);
  hipLaunchKernelGGL(k_lstm,  dim3(128),   dim3(256), 0, stream, xb, wfp, bias, hb, fl, out);
}

// Round 2
// 4602.345 us; speedup vs baseline: 1.2941x; 1.2941x over previous
//
#include <hip/hip_runtime.h>

typedef __attribute__((ext_vector_type(8))) short short8;
typedef __attribute__((ext_vector_type(4))) float floatx4;

#define B_   128
#define T_   1024
#define D_   256
#define HS_  512

// workspace layout (bytes)
#define OFF_X   0ull
#define SZ_X    ((size_t)B_*T_*D_*2)            // 64 MiB  x in bf16
#define OFF_W   (OFF_X + SZ_X)
#define SZ_W    ((size_t)16*4*48*64*8*2)        // 3 MiB   weight fragments
#define OFF_H   (OFF_W + SZ_W)
#define SZ_H    ((size_t)2*B_*HS_*4)            // 512 KiB tagged h double buffer (u32/col)

__device__ inline unsigned short f2bf(float f){
  union { float f; unsigned u; } v; v.f = f;
  unsigned r = v.u + 0x7FFFu + ((v.u >> 16) & 1u);
  return (unsigned short)(r >> 16);
}

// ---- zero parity-0 of tagged h buffer (value 0, tag 0 == h(0)) ----
// parity-1 keeps the 0xAA poison: tag 0xAAAA never matches any step tag.
__global__ void k_zero(unsigned* __restrict__ hbuf32){
  int i = blockIdx.x*256 + threadIdx.x;
  if (i < B_*HS_) hbuf32[i] = 0u;
}

// ---- convert x fp32 -> bf16 ----
__global__ void k_convx(const float* __restrict__ x, unsigned short* __restrict__ xb){
  size_t i = ((size_t)blockIdx.x*256 + threadIdx.x)*8;
  const float* s = x + i;
  short8 r;
#pragma unroll
  for (int j=0;j<8;j++) r[j] = (short)f2bf(s[j]);
  *(short8*)(void*)(xb + i) = r;
}

// ---- pre-swizzle [W;U] into MFMA B-fragment order, bf16 ----
// flat = (((sub*4 + w)*24 + kt)*2 + nt)*64 + lane, 8 bf16 per flat entry
//   K   = kt*32 + (lane>>4)*8 + j
// GATE-PAIRING column permutation: output col c = lane&15 of acc_nt maps to
//   weight col = gate*HS + sub*32 + w*8 + (lane&7),  gate = nt*2 + ((lane>>3)&1)
__global__ void k_wfrag(const float* __restrict__ W, const float* __restrict__ U,
                        unsigned short* __restrict__ wf){
  int flat = blockIdx.x*256 + threadIdx.x;       // 0..196607
  int lane = flat & 63;
  int rest = flat >> 6;
  int nt   = rest & 1;
  int kt   = (rest >> 1) % 24;
  int sw   = (rest >> 1) / 24;                   // sub*4 + w
  int w    = sw & 3;
  int sub  = sw >> 2;
  int gate = nt*2 + ((lane >> 3) & 1);
  int colg = gate*HS_ + sub*32 + w*8 + (lane & 7);
  int kbase = kt*32 + (lane >> 4)*8;
  short8 r;
#pragma unroll
  for (int j=0;j<8;j++){
    int k = kbase + j;
    float v = (k < D_) ? W[(size_t)k*2048 + colg] : U[(size_t)(k-D_)*2048 + colg];
    r[j] = (short)f2bf(v);
  }
  *(short8*)(void*)(wf + (size_t)flat*8) = r;
}

// ---- persistent recurrence kernel, seqlock-tagged h exchange ----
// grid = 128 WGs x 256 thr. group = wg>>4 owns batch rows [16g,16g+16);
// sub = wg&15 owns h cols [32 sub, 32 sub+32); wave w owns h cols w*8..w*8+8
// across all 4 gates (gate pairing). K=768 MFMA 16x16x32 bf16, register B.
//
// h exchange: each col is a tagged u32 (bf16 | tag<<16), stored as atomic u64
// col-pairs (sc1). Consumer loads its slice and retries until every tag == t.
// No flags, no vmcnt(0) drain, no separate poll round-trip. WAR is safe by
// causality: a tag t+2 store requires all WGs produced t+1, hence consumed t.
// LDS A-tile double-buffered -> one raw s_barrier per step (no vmcnt drain).
__global__ __launch_bounds__(256, 1) void k_lstm(
  const unsigned short* __restrict__ xb,
  const unsigned short* __restrict__ wf,
  const float* __restrict__ bias,
  unsigned* __restrict__ hbuf,
  float* __restrict__ out)
{
  // swizzled fragments: idx(kt,q,row) = kt*512 + (q*16 + (row ^ ((q<<1)|(kt&1))))*8
  __shared__ unsigned short A_lds[2][16*512];    // 2 x 16 KiB, parity = t&1

  const int wg    = blockIdx.x;
  const int group = wg >> 4, sub = wg & 15;
  const int tid   = threadIdx.x;
  const int wave  = tid >> 6, lane = tid & 63;
  const int g16   = group*16;

  // B fragments: 48 x 16B/lane, resident all 1024 steps
  short8 bw[48];
  {
    const unsigned short* wp = wf + (size_t)(sub*4 + wave)*48*512 + (size_t)lane*8;
#pragma unroll
    for (int i=0;i<48;i++) bw[i] = *(const short8*)(const void*)(wp + i*512);
  }

  // elementwise geometry: one h-col per lane, 4 rows
  const int bit3 = (lane >> 3) & 1;
  const int hcol = sub*32 + wave*8 + (lane & 7);
  const int r0   = (lane >> 4) * 4;
  const float b0 = bias[bit3*HS_ + hcol];        // i | f
  const float b1 = bias[(2+bit3)*HS_ + hcol];    // g | o

  // MFMA A-fragment geometry
  const int arow = lane & 15, aq = lane >> 4;
  const unsigned short* xbase = xb + ((size_t)(g16 + arow)*T_)*D_ + aq*8;
  const int se = (aq*16 + (arow ^ (aq<<1)      ))*8;
  const int so = (aq*16 + (arow ^ ((aq<<1)|1)  ))*8;

  // h staging geometry: thread owns cols [4hc,4hc+4) x rows {2j+rbase}
  const int hc    = tid & 127;
  const int kt_l  = hc >> 3, qs = (hc >> 1) & 3, half = hc & 1;
  const int es    = (qs << 1) | (kt_l & 1);
  const int rbase = tid >> 7;

  const size_t HSQ = (size_t)B_*T_*HS_;
  float cc[4] = {0.f,0.f,0.f,0.f};               // c-state (bit3=1 lanes)

  short8 xfA[8], xfB[8];
#pragma unroll
  for (int kt=0;kt<8;kt++) xfA[kt] = *(const short8*)(const void*)(xbase + kt*32);

#define LOADH(hsrc, hv)                                                        \
  _Pragma("unroll")                                                            \
  for (int j=0;j<8;j++){                                                       \
    const unsigned* p = (hsrc) + (size_t)(g16 + 2*j + rbase)*HS_ + hc*4;       \
    hv[2*j]   = __hip_atomic_load((const unsigned long long*)(const void*)p,   \
                  __ATOMIC_RELAXED, __HIP_MEMORY_SCOPE_AGENT);                 \
    hv[2*j+1] = __hip_atomic_load((const unsigned long long*)(const void*)(p+2),\
                  __ATOMIC_RELAXED, __HIP_MEMORY_SCOPE_AGENT);                 \
  }

#define LSTM_STEP(TT, XC, XN) {                                                \
  const unsigned* hsrc = hbuf + (size_t)((TT)&1)*B_*HS_;                       \
  unsigned long long hv[16];                                                   \
  /* optimistic first tagged-load attempt (latency hides under x-MFMA) */      \
  LOADH(hsrc, hv);                                                             \
  /* x prefetch t+1 */                                                         \
  { int tn = (TT)+1 < T_ ? (TT)+1 : T_-1;                                      \
    const unsigned short* xp = xbase + (size_t)tn*D_;                          \
    _Pragma("unroll")                                                          \
    for (int kt=0;kt<8;kt++) XN[kt] = *(const short8*)(const void*)(xp+kt*32); \
  }                                                                            \
  /* x-part MFMA from registers */                                             \
  floatx4 acc0 = {0.f,0.f,0.f,0.f}, acc1 = {0.f,0.f,0.f,0.f};                  \
  _Pragma("unroll")                                                            \
  for (int kt=0;kt<8;kt++){                                                    \
    acc0 = __builtin_amdgcn_mfma_f32_16x16x32_bf16(XC[kt], bw[kt*2+0], acc0, 0,0,0); \
    acc1 = __builtin_amdgcn_mfma_f32_16x16x32_bf16(XC[kt], bw[kt*2+1], acc1, 0,0,0); \
  }                                                                            \
  /* verify tags; slow path: probe one col-pair per producer, then reload */   \
  for (;;){                                                                    \
    unsigned bad = 0u;                                                         \
    _Pragma("unroll")                                                          \
    for (int j=0;j<16;j++) bad |= (unsigned)(hv[j] >> 48) ^ (unsigned)(TT);    \
    if (__all((int)(bad == 0u))) break;                                        \
    const unsigned* hpp = hsrc + (size_t)(g16+15)*HS_ + (size_t)(lane & 15)*32;\
    while (!__all((int)((unsigned)(__hip_atomic_load(                          \
             (const unsigned long long*)(const void*)hpp,                      \
             __ATOMIC_RELAXED, __HIP_MEMORY_SCOPE_AGENT) >> 48)                \
             == (unsigned)(TT)))) {}                                           \
    LOADH(hsrc, hv);                                                           \
  }                                                                            \
  /* strip tags, stage into swizzled fragments (conflict-free) */              \
  _Pragma("unroll")                                                            \
  for (int j=0;j<8;j++){                                                       \
    int row = 2*j + rbase;                                                     \
    unsigned lo = (unsigned)(hv[2*j]   & 0xFFFFu) | ((unsigned)(hv[2*j]  >>32) << 16); \
    unsigned hi = (unsigned)(hv[2*j+1] & 0xFFFFu) | ((unsigned)(hv[2*j+1]>>32) << 16); \
    *(unsigned long long*)(void*)&A_lds[(TT)&1][kt_l*512 + (qs*16 + (row ^ es))*8      \
                                        + half*4]                             \
      = (unsigned long long)lo | ((unsigned long long)hi << 32);               \
  }                                                                            \
  asm volatile("s_waitcnt lgkmcnt(0)" ::: "memory");                           \
  __builtin_amdgcn_s_barrier();                                                \
  asm volatile("" ::: "memory");                                               \
  /* h-part MFMA (K=512) */                                                    \
  _Pragma("unroll")                                                            \
  for (int kt=0;kt<16;kt++){                                                   \
    short8 a = *(const short8*)(const void*)&A_lds[(TT)&1][kt*512 + ((kt&1) ? so : se)]; \
    acc0 = __builtin_amdgcn_mfma_f32_16x16x32_bf16(a, bw[(8+kt)*2+0], acc0, 0,0,0); \
    acc1 = __builtin_amdgcn_mfma_f32_16x16x32_bf16(a, bw[(8+kt)*2+1], acc1, 0,0,0); \
  }                                                                            \
  /* LSTM cell: (i,g) on bit3=0 lanes, (f,o)+c on bit3=1; xor-8 shfl */        \
  unsigned* hdst = hbuf + (size_t)(((TT)+1)&1)*B_*HS_;                         \
  float oh[4], op[4];                                                          \
  _Pragma("unroll")                                                            \
  for (int r=0;r<4;r++){                                                       \
    float a0 = acc0[r] + b0;                                                   \
    float a1 = acc1[r] + b1;                                                   \
    float s0 = 1.f/(1.f + __expf(-a0));            /* sig(i) | sig(f) */       \
    float e1 = __expf(bit3 ? -a1 : 2.f*a1);                                    \
    float s1 = bit3 ? 1.f/(1.f+e1) : 1.f - 2.f/(e1+1.f); /* sig(o)|tanh(g) */  \
    float p  = s0 * s1;                                                        \
    float pr = __shfl_xor(p, 8, 64);                                           \
    cc[r] = s0*cc[r] + pr;                         /* f*c + i*g  (bit3=1) */   \
    float th = 1.f - 2.f/(__expf(2.f*cc[r])+1.f);                              \
    float hval = s1 * th;                          /* o*tanh(c)  (bit3=1) */   \
    float hprt = __shfl_xor(hval, 1, 64);                                      \
    oh[r] = hval; op[r] = hprt;                                                \
    if ((lane & 9) == 8){  /* tagged h store FIRST -- it IS the signal */      \
      unsigned ta = (unsigned)f2bf(hval) | ((unsigned)((TT)+1) << 16);         \
      unsigned tb = (unsigned)f2bf(hprt) | ((unsigned)((TT)+1) << 16);         \
      __hip_atomic_store(                                                      \
        (unsigned long long*)(void*)(hdst + (size_t)(g16+r0+r)*HS_ + hcol),    \
        (unsigned long long)ta | ((unsigned long long)tb << 32),               \
        __ATOMIC_RELAXED, __HIP_MEMORY_SCOPE_AGENT);                           \
    }                                                                          \
  }                                                                            \
  /* out stores after all h stores -- off the critical path, no drain */       \
  _Pragma("unroll")                                                            \
  for (int r=0;r<4;r++){                                                       \
    if ((lane & 9) == 8){                                                      \
      float2 o2; o2.x = oh[r]; o2.y = op[r];                                   \
      *(float2*)(out + ((size_t)(g16+r0+r)*T_ + (TT))*HS_ + hcol) = o2;        \
    }                                                                          \
  }                                                                            \
  if ((TT) == T_-1){                                                           \
    _Pragma("unroll")                                                          \
    for (int r=0;r<4;r++){                                                     \
      float cp = __shfl_xor(cc[r], 1, 64);                                     \
      if ((lane & 9) == 8){                                                    \
        int gr = g16 + r0 + r;                                                 \
        float2 h2; h2.x = oh[r]; h2.y = op[r];                                 \
        *(float2*)(out + HSQ + (size_t)gr*HS_ + hcol) = h2;                    \
        float2 c2; c2.x = cc[r]; c2.y = cp;                                    \
        *(float2*)(out + HSQ + (size_t)B_*HS_ + (size_t)gr*HS_ + hcol) = c2;   \
      }                                                                        \
    }                                                                          \
  }                                                                            \
}

  for (int t=0; t<T_; t+=2){
    LSTM_STEP(t,   xfA, xfB);
    LSTM_STEP(t+1, xfB, xfA);
  }
#undef LSTM_STEP
#undef LOADH
}

extern "C" void kernel_launch(void* const* d_in, const int* in_sizes, int n_in,
                              void* d_out, int out_size, void* d_ws, size_t ws_size,
                              hipStream_t stream){
  (void)in_sizes; (void)n_in; (void)out_size; (void)ws_size;
  const float* x    = (const float*)d_in[0];
  const float* W    = (const float*)d_in[1];
  const float* U    = (const float*)d_in[2];
  const float* bias = (const float*)d_in[3];
  char* ws = (char*)d_ws;
  unsigned short* xb = (unsigned short*)(ws + OFF_X);
  unsigned short* wfp= (unsigned short*)(ws + OFF_W);
  unsigned*       hb = (unsigned*)(ws + OFF_H);
  float* out = (float*)d_out;

  hipLaunchKernelGGL(k_zero,  dim3(256),   dim3(256), 0, stream, hb);
  hipLaunchKernelGGL(k_convx, dim3((B_*T_*D_/8)/256), dim3(256), 0, stream, x, xb);
  hipLaunchKernelGGL(k_wfrag, dim3(768),   dim3(256), 0, stream, W, U, wfp);
  hipLaunchKernelGGL(k_lstm,  dim3(128),   dim3(256), 0, stream, xb, wfp, bias, hb, out);
}